// Round 8
// baseline (323.693 us; speedup 1.0000x reference)
//
#include <hip/hip_runtime.h>
#include <hip/hip_bf16.h>

#define S_LEN 2048
#define BATCH 4
#define DMODEL 1024
#define NHEAD 16
#define HDIM 64
#define E3 3072

typedef __bf16 bf16x8 __attribute__((ext_vector_type(8)));
typedef __bf16 bf16x4 __attribute__((ext_vector_type(4)));
typedef __bf16 bf16x2 __attribute__((ext_vector_type(2)));
typedef float f32x4 __attribute__((ext_vector_type(4)));

typedef const __attribute__((address_space(1))) void gvoid;
typedef __attribute__((address_space(3))) void lvoid;

// ---------------------------------------------------------------------------
// fp32 -> bf16 elementwise cast, 8 elems/thread
// ---------------------------------------------------------------------------
__global__ void cast_f32_bf16(const float* __restrict__ src, __bf16* __restrict__ dst) {
    int i = (blockIdx.x * 256 + threadIdx.x) * 8;
    float4 a = *(const float4*)(src + i);
    float4 b = *(const float4*)(src + i + 4);
    bf16x8 v;
    v[0] = (__bf16)a.x; v[1] = (__bf16)a.y; v[2] = (__bf16)a.z; v[3] = (__bf16)a.w;
    v[4] = (__bf16)b.x; v[5] = (__bf16)b.y; v[6] = (__bf16)b.z; v[7] = (__bf16)b.w;
    *(bf16x8*)(dst + i) = v;
}

// ---------------------------------------------------------------------------
// Tiled transpose + fp32->bf16 cast: dst[c][r] = (bf16)src[r][c]
// ---------------------------------------------------------------------------
__global__ void transpose_f32_bf16(const float* __restrict__ src, __bf16* __restrict__ dst,
                                   int R, int C) {
    __shared__ float tile[32][33];
    int c0 = blockIdx.x * 32, r0 = blockIdx.y * 32;
    int tx = threadIdx.x, ty = threadIdx.y;
#pragma unroll
    for (int i = 0; i < 32; i += 8)
        tile[ty + i][tx] = src[(size_t)(r0 + ty + i) * C + c0 + tx];
    __syncthreads();
#pragma unroll
    for (int i = 0; i < 32; i += 8)
        dst[(size_t)(c0 + ty + i) * R + r0 + tx] = (__bf16)tile[tx][ty + i];
}

// ---------------------------------------------------------------------------
// 256x256 deep-pipelined bf16 GEMM (8-phase-style), C = A @ BT^T.
// BK=64, 512 threads = 8 waves (2M x 4N), per-wave C = 128x64 (8x4 frags).
// - dbuf LDS 128 KB; ONE {vmcnt(0); raw s_barrier} per K-tile; next tile's 8
//   global_load_lds issued spread over the 4 compute phases (counted-wait
//   pipeline: at the boundary the only outstanding loads are tile-t's own).
// - T2 swizzle both-sides: global source col-chunk pre-swizzled by (row&7),
//   ds_read applies the same XOR -> conflict-free b128 fragment reads.
// - T5 setprio around each 16-MFMA phase.
// mode 0 (QKV): RoPE epilogue for n0<2048 (fp32, ds_swizzle lane^1 partner),
//   V written transposed to vtg for n0>=2048. mode 1: fp32 C.
// NOTE: raw s_barrier (NOT __syncthreads) - avoids the compiler's vmcnt(0)
// drain before barriers that capped the old structure.
// ---------------------------------------------------------------------------
__global__ __launch_bounds__(512) void gemm256(
    const __bf16* __restrict__ A, const __bf16* __restrict__ BT, void* __restrict__ C,
    int K, int aSB, int aSS, int cSB, int cSS, int mode,
    const float* __restrict__ cosb, const float* __restrict__ sinb,
    __bf16* __restrict__ vtg) {
    __shared__ __bf16 lA[2][16384];  // [buf][half(2) x 128 x 64]
    __shared__ __bf16 lB[2][16384];

    const int tid = threadIdx.x;
    const int lane = tid & 63;
    const int quad = (lane >> 4) & 3, l16 = lane & 15;
    const int wave = tid >> 6;
    const int wm = wave >> 2;   // 0..1 (M)
    const int wn = wave & 3;    // 0..3 (N)

    // T1 XCD swizzle (both grids %8==0)
    const int bid0 = blockIdx.y * gridDim.x + blockIdx.x;
    const int nwg = gridDim.x * gridDim.y;
    const int lid = (bid0 & 7) * (nwg >> 3) + (bid0 >> 3);
    const int bx = lid % gridDim.x;
    const int by = lid / gridDim.x;

    const int rm0 = by * 256;
    const int n0 = bx * 256;
    const int bb = rm0 / S_LEN;
    const int s0 = rm0 % S_LEN;

    // staging source (per-thread): 512 thr x 16B = 64 rows x 128B per round
    const int srow = tid >> 3;                          // 0..63
    const int scs = ((tid & 7) ^ (srow & 7)) * 8;       // pre-swizzled col chunk
    const __bf16* gA = A + (size_t)bb * aSB + (size_t)(s0 + srow) * aSS + scs;
    const __bf16* gB = BT + (size_t)(n0 + srow) * K + scs;
    const int ldsOff = wave * 512;  // elements; wave-uniform (lane*16B auto)

    f32x4 acc[8][4];
#pragma unroll
    for (int i = 0; i < 8; i++)
#pragma unroll
        for (int j = 0; j < 4; j++) acc[i][j] = (f32x4){0.f, 0.f, 0.f, 0.f};

    // prologue: stage K-tile 0 into buf 0 (8 gloads/thread)
#pragma unroll
    for (int h = 0; h < 2; h++) {
        __builtin_amdgcn_global_load_lds((gvoid*)(gA + (size_t)(h * 128) * aSS),
                                         (lvoid*)&lA[0][h * 8192 + ldsOff], 16, 0, 0);
        __builtin_amdgcn_global_load_lds((gvoid*)(gA + (size_t)(h * 128 + 64) * aSS),
                                         (lvoid*)&lA[0][h * 8192 + 4096 + ldsOff], 16, 0, 0);
        __builtin_amdgcn_global_load_lds((gvoid*)(gB + (size_t)(h * 128) * K),
                                         (lvoid*)&lB[0][h * 8192 + ldsOff], 16, 0, 0);
        __builtin_amdgcn_global_load_lds((gvoid*)(gB + (size_t)(h * 128 + 64) * K),
                                         (lvoid*)&lB[0][h * 8192 + 4096 + ldsOff], 16, 0, 0);
    }

    const int nT = K >> 6;
#pragma unroll 1
    for (int t = 0; t < nT; ++t) {
        // ---- K-tile boundary: own tile-t loads are the ONLY outstanding ----
        asm volatile("s_waitcnt vmcnt(0)" ::: "memory");
        __builtin_amdgcn_s_barrier();           // all waves' tile-t loads landed;
        asm volatile("" ::: "memory");          // no LDS read hoists above this
        __builtin_amdgcn_sched_barrier(0);

        const int cur = t & 1;
        const int kn = (t + 1) << 6;
        const bool more = (t + 1 < nT);
        const __bf16* lAc = lA[cur];
        const __bf16* lBc = lB[cur];

        bf16x8 bfr[4][2];
#pragma unroll
        for (int p = 0; p < 4; ++p) {
            // stage one half-tile of K-tile t+1 into buf cur^1 (2 gloads)
            if (more) {
                if (p < 2) {
                    const __bf16* g = gA + (size_t)(p * 128) * aSS + kn;
                    __builtin_amdgcn_global_load_lds(
                        (gvoid*)g, (lvoid*)&lA[cur ^ 1][p * 8192 + ldsOff], 16, 0, 0);
                    __builtin_amdgcn_global_load_lds(
                        (gvoid*)(g + (size_t)64 * aSS),
                        (lvoid*)&lA[cur ^ 1][p * 8192 + 4096 + ldsOff], 16, 0, 0);
                } else {
                    const __bf16* g = gB + (size_t)((p - 2) * 128) * K + kn;
                    __builtin_amdgcn_global_load_lds(
                        (gvoid*)g, (lvoid*)&lB[cur ^ 1][(p - 2) * 8192 + ldsOff], 16, 0, 0);
                    __builtin_amdgcn_global_load_lds(
                        (gvoid*)(g + (size_t)64 * K),
                        (lvoid*)&lB[cur ^ 1][(p - 2) * 8192 + 4096 + ldsOff], 16, 0, 0);
                }
            }
            // B fragments once per K-tile (phase 0), reused by all phases
            if (p == 0) {
#pragma unroll
                for (int nf = 0; nf < 4; nf++)
#pragma unroll
                    for (int kh = 0; kh < 2; kh++)
                        bfr[nf][kh] = *(const bf16x8*)&lBc[(wn >> 1) * 8192 +
                                                           ((wn & 1) * 64 + nf * 16 + l16) * 64 +
                                                           (((kh * 4 + quad) ^ (l16 & 7)) * 8)];
            }
            // A fragments for this phase's 2 M-frags
            bf16x8 afr[2][2];
#pragma unroll
            for (int m2 = 0; m2 < 2; m2++)
#pragma unroll
                for (int kh = 0; kh < 2; kh++)
                    afr[m2][kh] = *(const bf16x8*)&lAc[wm * 8192 +
                                                       ((p * 2 + m2) * 16 + l16) * 64 +
                                                       (((kh * 4 + quad) ^ (l16 & 7)) * 8)];
            __builtin_amdgcn_s_setprio(1);
#pragma unroll
            for (int m2 = 0; m2 < 2; m2++)
#pragma unroll
                for (int nf = 0; nf < 4; nf++) {
                    f32x4 a = acc[p * 2 + m2][nf];
                    a = __builtin_amdgcn_mfma_f32_16x16x32_bf16(afr[m2][0], bfr[nf][0], a, 0, 0, 0);
                    a = __builtin_amdgcn_mfma_f32_16x16x32_bf16(afr[m2][1], bfr[nf][1], a, 0, 0, 0);
                    acc[p * 2 + m2][nf] = a;
                }
            __builtin_amdgcn_s_setprio(0);
        }
    }

    // ---- epilogues ----
    if (mode == 0) {
        if (n0 < 2048) {
            // q/k: RoPE in fp32 (partner via ds_swizzle lane^1), single rounding
#pragma unroll
            for (int mf = 0; mf < 8; mf++) {
#pragma unroll
                for (int r = 0; r < 4; r++) {
                    const int s = s0 + wm * 128 + mf * 16 + quad * 4 + r;
                    __bf16* cRow =
                        (__bf16*)C + (size_t)bb * cSB + (size_t)s * cSS + n0 + wn * 64 + l16;
                    const float* cpr = cosb + s * HDIM;
                    const float* spr = sinb + s * HDIM;
#pragma unroll
                    for (int nf = 0; nf < 4; nf++) {
                        float x = acc[mf][nf][r];
                        float y = __int_as_float(
                            __builtin_amdgcn_ds_swizzle(__float_as_int(x), 0x041F));
                        float c = cpr[nf * 16 + l16];
                        float sn = spr[nf * 16 + l16];
                        float out = (l16 & 1) ? fmaf(y, sn, x * c) : fmaf(-y, sn, x * c);
                        cRow[nf * 16] = (__bf16)out;
                    }
                }
            }
        } else {
            // v: write transposed to vtg[(b*1024+vcol)][s] only
#pragma unroll
            for (int mf = 0; mf < 8; mf++)
#pragma unroll
                for (int nf = 0; nf < 4; nf++) {
                    const int vcol = (n0 - 2048) + wn * 64 + nf * 16 + l16;
                    const size_t vbase =
                        ((size_t)(bb * 1024 + vcol)) * S_LEN + s0 + wm * 128 + mf * 16 + quad * 4;
                    bf16x2 lo = {(__bf16)acc[mf][nf][0], (__bf16)acc[mf][nf][1]};
                    bf16x2 hi = {(__bf16)acc[mf][nf][2], (__bf16)acc[mf][nf][3]};
                    *(bf16x2*)(vtg + vbase) = lo;
                    *(bf16x2*)(vtg + vbase + 2) = hi;
                }
        }
    } else {
#pragma unroll
        for (int mf = 0; mf < 8; mf++) {
#pragma unroll
            for (int r = 0; r < 4; r++) {
                const int s = s0 + wm * 128 + mf * 16 + quad * 4 + r;
                float* cRow = (float*)C + (size_t)bb * cSB + (size_t)s * cSS + n0 + wn * 64 + l16;
#pragma unroll
                for (int nf = 0; nf < 4; nf++) cRow[nf * 16] = acc[mf][nf][r];
            }
        }
    }
}

// ---------------------------------------------------------------------------
// Flash attention, REGISTER-P (R5/R7 structure, 91.8 us measured). Swapped
// QK^T (mfma(K,Q)) puts a full q-row of scores in each lane; shared key
// permutation pi applied to BOTH lane-local P and the V fragment (2x
// ds_read_b64) makes PV legal with no cross-lane P movement and no P LDS.
// Strips sequential (independent chains schedule better than lockstep - R6).
// LDS 37 KB -> 4 blocks/CU. grid = (16, B*H). Plain __launch_bounds__(256)
// ((256,4) caused a 200 MB spill storm - R4).
// ---------------------------------------------------------------------------
#define VT_IDX(hd, t) ((hd) * 72 + ((hd) >> 4) * 8 + (t))

__global__ __launch_bounds__(256) void attn_kernel(const __bf16* __restrict__ qkv,
                                                   const __bf16* __restrict__ vt,
                                                   __bf16* __restrict__ ctx) {
    __shared__ __bf16 sK[2][64 * 72];
    __shared__ __bf16 sVT[2][64 * 72 + 32];

    const int tid = threadIdx.x, lane = tid & 63, wave = tid >> 6;
    const int quad = lane >> 4, l16 = lane & 15;

    const int bid0 = blockIdx.y * 16 + blockIdx.x;
    const int lid = (bid0 & 7) * 128 + (bid0 >> 3);
    const int pair = lid & 15;
    const int bh = lid >> 4;
    const int b = bh >> 4, h = bh & 15;

    const int qtA = pair, qtB = 31 - pair;
    const int s0A = qtA * 64 + wave * 16;
    const int s0B = qtB * 64 + wave * 16;

    const int srow = tid >> 2;
    const int c0 = (tid & 3) * 16;

    const float qscale = 0.125f * 1.44269504f;
    const __bf16* kBase = qkv + (size_t)(b * S_LEN + srow) * E3 + DMODEL + h * HDIM + c0;
    const __bf16* vBase = vt + ((size_t)bh * HDIM + srow) * S_LEN + c0;

    const __bf16* qbA = qkv + (size_t)(b * S_LEN + s0A + l16) * E3 + h * HDIM;
    const __bf16* qbB = qkv + (size_t)(b * S_LEN + s0B + l16) * E3 + h * HDIM;
    bf16x8 qfA0 = *(const bf16x8*)(qbA + quad * 8);
    bf16x8 qfA1 = *(const bf16x8*)(qbA + 32 + quad * 8);
    bf16x8 qfB0 = *(const bf16x8*)(qbB + quad * 8);
    bf16x8 qfB1 = *(const bf16x8*)(qbB + 32 + quad * 8);
#pragma unroll
    for (int i = 0; i < 8; i++) {
        qfA0[i] = (__bf16)((float)qfA0[i] * qscale);
        qfA1[i] = (__bf16)((float)qfA1[i] * qscale);
        qfB0[i] = (__bf16)((float)qfB0[i] * qscale);
        qfB1[i] = (__bf16)((float)qfB1[i] * qscale);
    }

    f32x4 oA[4], oB[4], lacA, lacB;
#pragma unroll
    for (int j = 0; j < 4; j++) {
        oA[j] = (f32x4){0.f, 0.f, 0.f, 0.f};
        oB[j] = (f32x4){0.f, 0.f, 0.f, 0.f};
    }
    lacA = (f32x4){0.f, 0.f, 0.f, 0.f};
    lacB = (f32x4){0.f, 0.f, 0.f, 0.f};

    bf16x8 ones;
#pragma unroll
    for (int i = 0; i < 8; i++) ones[i] = (__bf16)1.0f;

    const __bf16* kRow = kBase;
    const __bf16* vRow = vBase;
    bf16x8 k0 = *(const bf16x8*)kRow;
    bf16x8 k1 = *(const bf16x8*)(kRow + 8);
    bf16x8 v0 = *(const bf16x8*)vRow;
    bf16x8 v1 = *(const bf16x8*)(vRow + 8);

    const int nT = qtB + 1;
#pragma unroll 1
    for (int it = 0; it < nT; ++it) {
        const int t0 = it * 64;
        __bf16* sKc = sK[it & 1];
        __bf16* sVc = sVT[it & 1];
        *(bf16x8*)&sKc[srow * 72 + c0] = k0;
        *(bf16x8*)&sKc[srow * 72 + c0 + 8] = k1;
        *(bf16x8*)&sVc[VT_IDX(srow, c0)] = v0;
        *(bf16x8*)&sVc[VT_IDX(srow, c0 + 8)] = v1;
        __syncthreads();

        if (it + 1 < nT) {
            kRow += (size_t)64 * E3;
            vRow += 64;
            k0 = *(const bf16x8*)kRow;
            k1 = *(const bf16x8*)(kRow + 8);
            v0 = *(const bf16x8*)vRow;
            v1 = *(const bf16x8*)(vRow + 8);
        }

        // ================= strip B =================
        {
            f32x4 sc[4];
            __builtin_amdgcn_s_setprio(1);
#pragma unroll
            for (int jt = 0; jt < 4; jt++) {
                bf16x8 kf0 = *(const bf16x8*)&sKc[(jt * 16 + l16) * 72 + quad * 8];
                bf16x8 kf1 = *(const bf16x8*)&sKc[(jt * 16 + l16) * 72 + 32 + quad * 8];
                f32x4 z = (f32x4){0.f, 0.f, 0.f, 0.f};
                z = __builtin_amdgcn_mfma_f32_16x16x32_bf16(kf0, qfB0, z, 0, 0, 0);
                sc[jt] = __builtin_amdgcn_mfma_f32_16x16x32_bf16(kf1, qfB1, z, 0, 0, 0);
            }
            __builtin_amdgcn_s_setprio(0);

            float p[4][4];
            if (it == qtB) {
                const int qq = s0B + l16;
#pragma unroll
                for (int jt = 0; jt < 4; jt++)
#pragma unroll
                    for (int r = 0; r < 4; r++) {
                        int tt = t0 + jt * 16 + quad * 4 + r;
                        p[jt][r] = __builtin_exp2f((tt > qq) ? -1e9f : sc[jt][r]);
                    }
            } else {
#pragma unroll
                for (int jt = 0; jt < 4; jt++)
#pragma unroll
                    for (int r = 0; r < 4; r++) p[jt][r] = __builtin_exp2f(sc[jt][r]);
            }

            __builtin_amdgcn_s_setprio(1);
#pragma unroll
            for (int kt = 0; kt < 2; kt++) {
                bf16x8 pf;
#pragma unroll
                for (int r = 0; r < 4; r++) {
                    pf[r] = (__bf16)p[2 * kt][r];
                    pf[4 + r] = (__bf16)p[2 * kt + 1][r];
                }
#pragma unroll
                for (int jhd = 0; jhd < 4; jhd++) {
                    bf16x4 vlo = *(const bf16x4*)&sVc[VT_IDX(jhd * 16 + l16, kt * 32 + quad * 4)];
                    bf16x4 vhi = *(const bf16x4*)&sVc[VT_IDX(jhd * 16 + l16, kt * 32 + 16 + quad * 4)];
                    bf16x8 vf = __builtin_shufflevector(vlo, vhi, 0, 1, 2, 3, 4, 5, 6, 7);
                    oB[jhd] = __builtin_amdgcn_mfma_f32_16x16x32_bf16(pf, vf, oB[jhd], 0, 0, 0);
                }
                lacB = __builtin_amdgcn_mfma_f32_16x16x32_bf16(pf, ones, lacB, 0, 0, 0);
            }
            __builtin_amdgcn_s_setprio(0);
        }

        // ================= strip A =================
        if (it <= qtA) {
            f32x4 sc[4];
            __builtin_amdgcn_s_setprio(1);
#pragma unroll
            for (int jt = 0; jt < 4; jt++) {
                bf16x8 kf0 = *(const bf16x8*)&sKc[(jt * 16 + l16) * 72 + quad * 8];
                bf16x8 kf1 = *(const bf16x8*)&sKc[(jt * 16 + l16) * 72 + 32 + quad * 8];
                f32x4 z = (f32x4){0.f, 0.f, 0.f, 0.f};
                z = __builtin_amdgcn_mfma_f32_16x16x32_bf16(kf0, qfA0, z, 0, 0, 0);
                sc[jt] = __builtin_amdgcn_mfma_f32_16x16x32_bf16(kf1, qfA1, z, 0, 0, 0);
            }
            __builtin_amdgcn_s_setprio(0);

            float p[4][4];
            if (it == qtA) {
                const int qq = s0A + l16;
#pragma unroll
                for (int jt = 0; jt < 4; jt++)
#pragma unroll
                    for (int r = 0; r < 4; r++) {
                        int tt = t0 + jt * 16 + quad * 4 + r;
                        p[jt][r] = __builtin_exp2f((tt > qq) ? -1e9f : sc[jt][r]);
                    }
            } else {
#pragma unroll
                for (int jt = 0; jt < 4; jt++)
#pragma unroll
                    for (int r = 0; r < 4; r++) p[jt][r] = __builtin_exp2f(sc[jt][r]);
            }

            __builtin_amdgcn_s_setprio(1);
#pragma unroll
            for (int kt = 0; kt < 2; kt++) {
                bf16x8 pf;
#pragma unroll
                for (int r = 0; r < 4; r++) {
                    pf[r] = (__bf16)p[2 * kt][r];
                    pf[4 + r] = (__bf16)p[2 * kt + 1][r];
                }
#pragma unroll
                for (int jhd = 0; jhd < 4; jhd++) {
                    bf16x4 vlo = *(const bf16x4*)&sVc[VT_IDX(jhd * 16 + l16, kt * 32 + quad * 4)];
                    bf16x4 vhi = *(const bf16x4*)&sVc[VT_IDX(jhd * 16 + l16, kt * 32 + 16 + quad * 4)];
                    bf16x8 vf = __builtin_shufflevector(vlo, vhi, 0, 1, 2, 3, 4, 5, 6, 7);
                    oA[jhd] = __builtin_amdgcn_mfma_f32_16x16x32_bf16(pf, vf, oA[jhd], 0, 0, 0);
                }
                lacA = __builtin_amdgcn_mfma_f32_16x16x32_bf16(pf, ones, lacA, 0, 0, 0);
            }
            __builtin_amdgcn_s_setprio(0);
        }
    }

#pragma unroll
    for (int r = 0; r < 4; r++) {
        float inv = 1.f / lacA[r];
        size_t crow = (size_t)(b * S_LEN + s0A + quad * 4 + r) * DMODEL + h * HDIM + l16;
#pragma unroll
        for (int j = 0; j < 4; j++) ctx[crow + j * 16] = (__bf16)(oA[j][r] * inv);
    }
#pragma unroll
    for (int r = 0; r < 4; r++) {
        float inv = 1.f / lacB[r];
        size_t crow = (size_t)(b * S_LEN + s0B + quad * 4 + r) * DMODEL + h * HDIM + l16;
#pragma unroll
        for (int j = 0; j < 4; j++) ctx[crow + j * 16] = (__bf16)(oB[j][r] * inv);
    }
}

// ---------------------------------------------------------------------------
extern "C" void kernel_launch(void* const* d_in, const int* in_sizes, int n_in,
                              void* d_out, int out_size, void* d_ws, size_t ws_size,
                              hipStream_t stream) {
    const float* x = (const float*)d_in[0];      // (S,B,D) fp32
    const float* cosb = (const float*)d_in[2];   // (1,1,S,HD) fp32
    const float* sinb = (const float*)d_in[3];
    const float* Wqkv = (const float*)d_in[4];   // (D, 3D) fp32
    const float* Wout = (const float*)d_in[5];   // (D, D) fp32
    float* out = (float*)d_out;                  // (S,B,D) fp32

    char* ws = (char*)d_ws;
    __bf16* qkv = (__bf16*)ws;                                     // B*S*3D bf16 = 48 MB
    __bf16* ctx = (__bf16*)(ws + 50331648);                        // B*S*D  bf16 = 16 MB
    __bf16* WqkvT = (__bf16*)(ws + 50331648 + 16777216);           // 3D*D   bf16
    __bf16* WoutT = (__bf16*)(ws + 50331648 + 16777216 + 6291456); // D*D    bf16
    __bf16* xb = ctx;  // alias: xb dead before attn writes ctx
    __bf16* vtg = (__bf16*)d_out;  // VT scratch in d_out; dead before final GEMM

    cast_f32_bf16<<<(S_LEN * BATCH * DMODEL / 8) / 256, 256, 0, stream>>>(x, xb);
    transpose_f32_bf16<<<dim3(E3 / 32, DMODEL / 32), dim3(32, 8), 0, stream>>>(Wqkv, WqkvT, DMODEL, E3);
    transpose_f32_bf16<<<dim3(DMODEL / 32, DMODEL / 32), dim3(32, 8), 0, stream>>>(Wout, WoutT, DMODEL, DMODEL);

    // qkv = xb @ Wqkv, fused RoPE (q,k) + V-transpose -> vtg
    gemm256<<<dim3(E3 / 256, (BATCH * S_LEN) / 256), 512, 0, stream>>>(
        xb, WqkvT, qkv, DMODEL,
        /*aSB=*/DMODEL, /*aSS=*/BATCH * DMODEL,
        /*cSB=*/S_LEN * E3, /*cSS=*/E3, /*mode=*/0, cosb, sinb, vtg);

    attn_kernel<<<dim3(16, BATCH * NHEAD), 256, 0, stream>>>(qkv, vtg, ctx);

    // out = ctx @ Wout (fp32 out)
    gemm256<<<dim3(DMODEL / 256, (BATCH * S_LEN) / 256), 512, 0, stream>>>(
        ctx, WoutT, out, DMODEL,
        /*aSB=*/S_LEN * DMODEL, /*aSS=*/DMODEL,
        /*cSB=*/DMODEL, /*cSS=*/BATCH * DMODEL, /*mode=*/1, nullptr, nullptr, nullptr);
}